// Round 4
// baseline (525.023 us; speedup 1.0000x reference)
//
#include <hip/hip_runtime.h>

// DMT skeletonize: exact separable squared-EDT + 26-neighborhood local max.
// Shapes: img (4,1,160,160,160) f32. We work on squared distances only:
// sqrt is monotone and d2 values are distinct integers (<2^24) or 1e12, so
// all reference comparisons (d >= windowmax, d > 0) are decision-identical.
// INF arithmetic: 1e12f + r^2 rounds back to 1e12f for r^2 < 32768 in fp32
// (per-pass r^2 <= 159^2 = 25281), matching the reference's fp32 behavior
// bit-exactly on INF lines; finite values are exact integers < 2^24.

#define INF_F 1.0e12f

constexpr int NX = 160, NY = 160, NZ = 160, NB = 4;
constexpr int VOL   = NX * NY * NZ;        // 4,096,000 per batch
constexpr int TOTAL = NB * VOL;            // 16,384,000
constexpr int BLK   = 256;

// ---------------------------------------------------------------------------
// Pass 1 (along X, contiguous): fused binarization. f[j] = (img[j] > 0.5) ? 0 : INF.
// Outward search for nearest "zero" (img > 0.5); exact early exit at r*r >= cur.
__global__ void edt_pass_x(const float* __restrict__ img, float* __restrict__ out) {
    int idx = blockIdx.x * BLK + threadIdx.x;
    if (idx >= TOTAL) return;
    int x = idx % NX;
    int lineBase = idx - x;
    float cur = (img[idx] > 0.5f) ? 0.0f : INF_F;
    // r2 = r*r via incremental odd-number add
    float r2 = 1.0f, odd = 1.0f;
    for (int r = 1; r < NX; ++r) {
        if (r2 >= cur) break;               // no farther candidate can win (g >= 0)
        int xl = x - r, xr = x + r;
        if (xl >= 0 && img[lineBase + xl] > 0.5f) cur = r2;
        if (xr < NX && img[lineBase + xr] > 0.5f) cur = fminf(cur, r2);
        odd += 2.0f; r2 += odd;             // (r+1)^2 = r^2 + (2r+1)
    }
    out[idx] = cur;
}

// ---------------------------------------------------------------------------
// General pass along an axis with element-stride S (length 160).
// d2out[i] = min_j g[j] + (i-j)^2, exact with outward search + early break:
// if r^2 >= cur then every |i-j| >= r candidate is >= r^2 >= cur (g >= 0).
template <int S>
__global__ void edt_pass_axis(const float* __restrict__ g, float* __restrict__ out) {
    int idx = blockIdx.x * BLK + threadIdx.x;
    if (idx >= TOTAL) return;
    int c = (idx / S) % 160;                // coordinate along this axis
    float cur = g[idx];                     // j == i candidate
    float r2 = 1.0f, odd = 1.0f;
    for (int r = 1; r < 160; ++r) {
        if (r2 >= cur) break;
        if (c - r >= 0)  cur = fminf(cur, g[idx - r * S] + r2);
        if (c + r < 160) cur = fminf(cur, g[idx + r * S] + r2);
        odd += 2.0f; r2 += odd;
    }
    out[idx] = cur;
}

// ---------------------------------------------------------------------------
// Skeleton: keep voxels that are 26-neighborhood maxima of d2 with d2 > 0,
// then multiply by img. Boundary = skip OOB neighbors ('SAME' pads with -inf).
__global__ void skel_kernel(const float* __restrict__ d2,
                            const float* __restrict__ img,
                            float* __restrict__ out) {
    int idx = blockIdx.x * BLK + threadIdx.x;
    if (idx >= TOTAL) return;
    int x = idx % NX;
    int t = idx / NX;
    int y = t % NY;
    int z = (t / NY) % NZ;

    int dz0 = (z == 0) ? 0 : -1, dz1 = (z == NZ - 1) ? 0 : 1;
    int dy0 = (y == 0) ? 0 : -1, dy1 = (y == NY - 1) ? 0 : 1;
    int dx0 = (x == 0) ? 0 : -1, dx1 = (x == NX - 1) ? 0 : 1;

    float center = d2[idx];
    float mx = center;                      // window includes the center
    for (int dz = dz0; dz <= dz1; ++dz)
        for (int dy = dy0; dy <= dy1; ++dy) {
            const float* row = d2 + idx + (dz * NY + dy) * NX;
            for (int dx = dx0; dx <= dx1; ++dx)
                mx = fmaxf(mx, row[dx]);
        }
    float s = (center >= mx && center > 0.0f) ? 1.0f : 0.0f;
    out[idx] = s * img[idx];
}

// ---------------------------------------------------------------------------
extern "C" void kernel_launch(void* const* d_in, const int* in_sizes, int n_in,
                              void* d_out, int out_size, void* d_ws, size_t ws_size,
                              hipStream_t stream) {
    const float* img = (const float*)d_in[0];
    float* outp = (float*)d_out;
    float* ws   = (float*)d_ws;             // needs >= TOTAL*4 = 65.5 MB

    int grid = (TOTAL + BLK - 1) / BLK;     // 64,000 blocks exactly

    // K1: X-pass (fused binarize): img -> ws
    edt_pass_x<<<grid, BLK, 0, stream>>>(img, ws);
    // K2: Y-pass (stride 160): ws -> d_out (used as scratch)
    edt_pass_axis<160><<<grid, BLK, 0, stream>>>(ws, outp);
    // K3: Z-pass (stride 160*160): d_out -> ws
    edt_pass_axis<160 * 160><<<grid, BLK, 0, stream>>>(outp, ws);
    // K4: skeleton + multiply: (ws = final d2, img) -> d_out
    skel_kernel<<<grid, BLK, 0, stream>>>(ws, img, outp);
}

// Round 6
// 357.530 us; speedup vs baseline: 1.4685x; 1.4685x over previous
//
#include <hip/hip_runtime.h>

// DMT skeletonize: exact separable squared-EDT + 26-neighborhood local max.
// Shapes: img (4,1,160,160,160) f32. We work on squared distances only:
// sqrt is monotone and d2 values are distinct integers (<2^24) or 1e12, so
// all reference comparisons (d >= windowmax, d > 0) are decision-identical.
// INF arithmetic: 1e12f + r^2 rounds back to 1e12f for r^2 < 32768 in fp32
// (per-pass r^2 <= 159^2 = 25281), matching the reference bit-exactly.

#define INF_F 1.0e12f

constexpr int NX = 160, NY = 160, NZ = 160, NB = 4;
constexpr int VOL   = NX * NY * NZ;        // 4,096,000 per batch
constexpr int TOTAL = NB * VOL;            // 16,384,000
constexpr int BLK   = 256;

// ---------------------------------------------------------------------------
// Pass 1 (along X, contiguous): fused binarization. f[j] = (img[j] > 0.5) ? 0 : INF.
// Outward search for nearest "zero" (img > 0.5); exact early exit at r*r >= cur.
__global__ void edt_pass_x(const float* __restrict__ img, float* __restrict__ out) {
    int idx = blockIdx.x * BLK + threadIdx.x;
    if (idx >= TOTAL) return;
    int x = idx % NX;
    int lineBase = idx - x;
    float cur = (img[idx] > 0.5f) ? 0.0f : INF_F;
    float r2 = 1.0f, odd = 1.0f;
    for (int r = 1; r < NX; ++r) {
        if (r2 >= cur) break;               // no farther candidate can win (g >= 0)
        int xl = x - r, xr = x + r;
        if (xl >= 0 && img[lineBase + xl] > 0.5f) cur = r2;
        if (xr < NX && img[lineBase + xr] > 0.5f) cur = fminf(cur, r2);
        odd += 2.0f; r2 += odd;             // (r+1)^2 = r^2 + (2r+1)
    }
    out[idx] = cur;
}

// ---------------------------------------------------------------------------
// General pass along an axis with element-stride S (length 160).
// d2out[i] = min_j g[j] + (i-j)^2, exact with outward search + early break.
template <int S>
__global__ void edt_pass_axis(const float* __restrict__ g, float* __restrict__ out) {
    int idx = blockIdx.x * BLK + threadIdx.x;
    if (idx >= TOTAL) return;
    int c = (idx / S) % 160;                // coordinate along this axis
    float cur = g[idx];                     // j == i candidate
    float r2 = 1.0f, odd = 1.0f;
    for (int r = 1; r < 160; ++r) {
        if (r2 >= cur) break;
        if (c - r >= 0)  cur = fminf(cur, g[idx - r * S] + r2);
        if (c + r < 160) cur = fminf(cur, g[idx + r * S] + r2);
        odd += 2.0f; r2 += odd;
    }
    out[idx] = cur;
}

// ---------------------------------------------------------------------------
// Skeleton v2: 4 outputs/thread, fully unrolled 9-row window, replicate-clamp
// boundaries (equivalent to skip-OOB for a max window: the clamped index
// always duplicates an element already inside the window). 27 independent
// loads per thread -> deep MLP/ILP; compile-time loop bounds -> full unroll.
__global__ void skel_kernel(const float* __restrict__ d2,
                            const float* __restrict__ img,
                            float* __restrict__ out) {
    int tid = blockIdx.x * BLK + threadIdx.x;
    if (tid >= TOTAL / 4) return;
    int idx4 = tid * 4;
    int x4 = idx4 % NX;                     // multiple of 4 (160 % 4 == 0)
    int t  = idx4 / NX;                     // global line id (incl. batch)
    int y  = t % NY;
    int z  = (t / NY) % NZ;                 // z within batch; window stays in-batch
    int lineBase = idx4 - x4;               // flat offset of this row's start

    // clamped neighbor offsets (branchless)
    const int yoff[3] = { (y > 0) ? -NX : 0,        0, (y < NY - 1) ? NX : 0 };
    const int zoff[3] = { (z > 0) ? -NX * NY : 0,   0, (z < NZ - 1) ? NX * NY : 0 };
    const int xl = (x4 > 0) ? x4 - 1 : 0;           // clamp(x4-1)
    const int xr = (x4 + 4 < NX) ? x4 + 4 : NX - 1; // clamp(x4+4)

    float4 center = make_float4(0.f, 0.f, 0.f, 0.f);
    float4 mx     = make_float4(-1.f, -1.f, -1.f, -1.f);

    #pragma unroll
    for (int iz = 0; iz < 3; ++iz) {
        #pragma unroll
        for (int iy = 0; iy < 3; ++iy) {
            const float* row = d2 + lineBase + zoff[iz] + yoff[iy];
            float4 m = *reinterpret_cast<const float4*>(row + x4);
            float  L = row[xl];
            float  R = row[xr];
            if (iz == 1 && iy == 1) center = m;
            // horizontal 3-window maxes (clang fuses to v_max3_f32)
            mx.x = fmaxf(mx.x, fmaxf(fmaxf(L,   m.x), m.y));
            mx.y = fmaxf(mx.y, fmaxf(fmaxf(m.x, m.y), m.z));
            mx.z = fmaxf(mx.z, fmaxf(fmaxf(m.y, m.z), m.w));
            mx.w = fmaxf(mx.w, fmaxf(fmaxf(m.z, m.w), R));
        }
    }

    float4 iv = *reinterpret_cast<const float4*>(img + idx4);
    float4 o;
    o.x = (center.x >= mx.x && center.x > 0.0f) ? iv.x : 0.0f;
    o.y = (center.y >= mx.y && center.y > 0.0f) ? iv.y : 0.0f;
    o.z = (center.z >= mx.z && center.z > 0.0f) ? iv.z : 0.0f;
    o.w = (center.w >= mx.w && center.w > 0.0f) ? iv.w : 0.0f;
    *reinterpret_cast<float4*>(out + idx4) = o;
}

// ---------------------------------------------------------------------------
extern "C" void kernel_launch(void* const* d_in, const int* in_sizes, int n_in,
                              void* d_out, int out_size, void* d_ws, size_t ws_size,
                              hipStream_t stream) {
    const float* img = (const float*)d_in[0];
    float* outp = (float*)d_out;
    float* ws   = (float*)d_ws;             // needs >= TOTAL*4 = 65.5 MB

    int grid = (TOTAL + BLK - 1) / BLK;     // 64,000 blocks

    // K1: X-pass (fused binarize): img -> ws
    edt_pass_x<<<grid, BLK, 0, stream>>>(img, ws);
    // K2: Y-pass (stride 160): ws -> d_out (used as scratch)
    edt_pass_axis<160><<<grid, BLK, 0, stream>>>(ws, outp);
    // K3: Z-pass (stride 160*160): d_out -> ws
    edt_pass_axis<160 * 160><<<grid, BLK, 0, stream>>>(outp, ws);
    // K4: skeleton + multiply, 4 voxels/thread: (ws = final d2, img) -> d_out
    int grid4 = (TOTAL / 4 + BLK - 1) / BLK; // 16,000 blocks
    skel_kernel<<<grid4, BLK, 0, stream>>>(ws, img, outp);
}

// Round 7
// 266.018 us; speedup vs baseline: 1.9736x; 1.3440x over previous
//
#include <hip/hip_runtime.h>

// DMT skeletonize: exact separable squared-EDT + 26-neighborhood local max.
// img (4,1,160,160,160) f32. All work on squared distances (sqrt elision is
// decision-identical: values are exact integers < 2^24 or the 1e12 sentinel).
// INF arithmetic: 1e12f + r^2 rounds back to 1e12f for r^2 < 32768 in fp32
// (per-pass r^2 <= 159^2 = 25281) -> bit-exact vs the reference.

#define INF_F 1.0e12f

constexpr int NX = 160, NY = 160, NZ = 160, NB = 4;
constexpr int VOL   = NX * NY * NZ;        // 4,096,000 per batch
constexpr int TOTAL = NB * VOL;            // 16,384,000
constexpr int NROWS = NB * NZ * NY;        // 102,400 x-rows
constexpr int BLK   = 256;

// ---------------------------------------------------------------------------
// Wave-wide inclusive prefix-max / suffix-min scans (64 lanes).
__device__ inline int wave_prefmax(int v) {
    #pragma unroll
    for (int off = 1; off < 64; off <<= 1) {
        int o = __shfl_up(v, off, 64);     // lanes < off keep own value
        v = max(v, o);
    }
    return v;
}
__device__ inline int wave_sufmin(int v) {
    #pragma unroll
    for (int off = 1; off < 64; off <<= 1) {
        int o = __shfl_down(v, off, 64);   // lanes >= 64-off keep own value
        v = min(v, o);
    }
    return v;
}

__device__ inline float edt1d_combine(int x, int lz, int rz) {
    // lz: nearest zero-site index <= x (sentinel -1048576 if none)
    // rz: nearest zero-site index >= x (sentinel +1048576 if none)
    float dl2 = (lz >= 0)  ? (float)((x - lz) * (x - lz)) : INF_F;
    float dr2 = (rz < 1000)? (float)((rz - x) * (rz - x)) : INF_F;
    return fminf(dl2, dr2);
}

// ---------------------------------------------------------------------------
// Pass 1 (along X): exact binary 1-D EDT via wave scans. One wave per row of
// 160 (3 chunks of 64/64/32). No divergence, no data-dependent loops, fully
// coalesced loads/stores. Zero-site := img > 0.5 (f = 0 there, INF elsewhere).
__global__ void edt_pass_x_scan(const float* __restrict__ img,
                                float* __restrict__ out) {
    int gw = blockIdx.x * (BLK / 64) + (threadIdx.x >> 6);   // wave id = row id
    if (gw >= NROWS) return;
    int lane = threadIdx.x & 63;
    int b = gw * NX;

    float a0 = img[b + lane];
    float a1 = img[b + 64 + lane];
    float a2 = (lane < 32) ? img[b + 128 + lane] : 0.0f;     // masked tail
    bool z0 = a0 > 0.5f;
    bool z1 = a1 > 0.5f;
    bool z2 = (lane < 32) && (a2 > 0.5f);

    const int NEG = -1048576, POS = 1048576;

    // left scan: last zero-site position <= x
    int l0 = wave_prefmax(z0 ? lane : NEG);
    int c  = __shfl(l0, 63, 64);
    int l1 = max(wave_prefmax(z1 ? 64 + lane : NEG), c);
    c      = __shfl(l1, 63, 64);
    int l2 = max(wave_prefmax(z2 ? 128 + lane : NEG), c);

    // right scan: next zero-site position >= x
    int r2v = wave_sufmin(z2 ? 128 + lane : POS);
    int cr  = __shfl(r2v, 0, 64);
    int r1  = min(wave_sufmin(z1 ? 64 + lane : POS), cr);
    cr      = __shfl(r1, 0, 64);
    int r0  = min(wave_sufmin(z0 ? lane : POS), cr);

    out[b + lane]      = edt1d_combine(lane,       l0, r0);
    out[b + 64 + lane] = edt1d_combine(64 + lane,  l1, r1);
    if (lane < 32)
        out[b + 128 + lane] = edt1d_combine(128 + lane, l2, r2v);
}

// ---------------------------------------------------------------------------
// Passes 2/3 (axis with element-stride S, length 160), 4 voxels per thread.
// d2out[i] = min_j g[j] + (i-j)^2, outward search, shared break on 4-way max.
// Extra iterations for converged components only add valid candidates (exact).
template <int S>
__global__ void edt_pass_axis4(const float* __restrict__ g,
                               float* __restrict__ out) {
    int tid = blockIdx.x * BLK + threadIdx.x;
    if (tid >= TOTAL / 4) return;
    int idx4 = tid * 4;                     // 4 consecutive x, same axis coord
    int c = (idx4 / S) % 160;
    float4 cur = *reinterpret_cast<const float4*>(g + idx4);
    float r2 = 1.0f, odd = 1.0f;
    for (int r = 1; r < 160; ++r) {
        float m = fmaxf(fmaxf(cur.x, cur.y), fmaxf(cur.z, cur.w));
        if (r2 >= m) break;                 // all 4 converged (g >= 0)
        if (c - r >= 0) {
            float4 u = *reinterpret_cast<const float4*>(g + idx4 - r * S);
            cur.x = fminf(cur.x, u.x + r2); cur.y = fminf(cur.y, u.y + r2);
            cur.z = fminf(cur.z, u.z + r2); cur.w = fminf(cur.w, u.w + r2);
        }
        if (c + r < 160) {
            float4 d = *reinterpret_cast<const float4*>(g + idx4 + r * S);
            cur.x = fminf(cur.x, d.x + r2); cur.y = fminf(cur.y, d.y + r2);
            cur.z = fminf(cur.z, d.z + r2); cur.w = fminf(cur.w, d.w + r2);
        }
        odd += 2.0f; r2 += odd;             // (r+1)^2 = r^2 + (2r+1)
    }
    *reinterpret_cast<float4*>(out + idx4) = cur;
}

// ---------------------------------------------------------------------------
// Skeleton: 4 outputs/thread, fully unrolled 3x3 row window, replicate-clamp
// boundaries (decision-identical to skip-OOB for a max window).
__global__ void skel_kernel(const float* __restrict__ d2,
                            const float* __restrict__ img,
                            float* __restrict__ out) {
    int tid = blockIdx.x * BLK + threadIdx.x;
    if (tid >= TOTAL / 4) return;
    int idx4 = tid * 4;
    int x4 = idx4 % NX;                     // multiple of 4
    int t  = idx4 / NX;
    int y  = t % NY;
    int z  = (t / NY) % NZ;
    int lineBase = idx4 - x4;

    const int yoff[3] = { (y > 0) ? -NX : 0,        0, (y < NY - 1) ? NX : 0 };
    const int zoff[3] = { (z > 0) ? -NX * NY : 0,   0, (z < NZ - 1) ? NX * NY : 0 };
    const int xl = (x4 > 0) ? x4 - 1 : 0;
    const int xr = (x4 + 4 < NX) ? x4 + 4 : NX - 1;

    float4 center = make_float4(0.f, 0.f, 0.f, 0.f);
    float4 mx     = make_float4(-1.f, -1.f, -1.f, -1.f);

    #pragma unroll
    for (int iz = 0; iz < 3; ++iz) {
        #pragma unroll
        for (int iy = 0; iy < 3; ++iy) {
            const float* row = d2 + lineBase + zoff[iz] + yoff[iy];
            float4 m = *reinterpret_cast<const float4*>(row + x4);
            float  L = row[xl];
            float  R = row[xr];
            if (iz == 1 && iy == 1) center = m;
            mx.x = fmaxf(mx.x, fmaxf(fmaxf(L,   m.x), m.y));
            mx.y = fmaxf(mx.y, fmaxf(fmaxf(m.x, m.y), m.z));
            mx.z = fmaxf(mx.z, fmaxf(fmaxf(m.y, m.z), m.w));
            mx.w = fmaxf(mx.w, fmaxf(fmaxf(m.z, m.w), R));
        }
    }

    float4 iv = *reinterpret_cast<const float4*>(img + idx4);
    float4 o;
    o.x = (center.x >= mx.x && center.x > 0.0f) ? iv.x : 0.0f;
    o.y = (center.y >= mx.y && center.y > 0.0f) ? iv.y : 0.0f;
    o.z = (center.z >= mx.z && center.z > 0.0f) ? iv.z : 0.0f;
    o.w = (center.w >= mx.w && center.w > 0.0f) ? iv.w : 0.0f;
    *reinterpret_cast<float4*>(out + idx4) = o;
}

// ---------------------------------------------------------------------------
extern "C" void kernel_launch(void* const* d_in, const int* in_sizes, int n_in,
                              void* d_out, int out_size, void* d_ws, size_t ws_size,
                              hipStream_t stream) {
    const float* img = (const float*)d_in[0];
    float* outp = (float*)d_out;
    float* ws   = (float*)d_ws;             // needs >= TOTAL*4 = 65.5 MB

    int gridRows = (NROWS + 3) / 4;         // 4 waves (rows) per 256-thr block
    int grid4    = (TOTAL / 4 + BLK - 1) / BLK;   // 16,000 blocks

    // K1: X-pass (wave-scan binary EDT): img -> ws
    edt_pass_x_scan<<<gridRows, BLK, 0, stream>>>(img, ws);
    // K2: Y-pass (stride 160), 4-wide: ws -> d_out (scratch)
    edt_pass_axis4<NX><<<grid4, BLK, 0, stream>>>(ws, outp);
    // K3: Z-pass (stride 25600), 4-wide: d_out -> ws
    edt_pass_axis4<NX * NY><<<grid4, BLK, 0, stream>>>(outp, ws);
    // K4: skeleton + multiply, 4 voxels/thread: (ws = final d2, img) -> d_out
    skel_kernel<<<grid4, BLK, 0, stream>>>(ws, img, outp);
}

// Round 8
// 230.045 us; speedup vs baseline: 2.2823x; 1.1564x over previous
//
#include <hip/hip_runtime.h>

// DMT skeletonize: exact separable squared-EDT + 26-neighborhood local max.
// img (4,1,160,160,160) f32. All work on squared distances (sqrt elision is
// decision-identical: values are exact integers < 2^24 or the 1e12 sentinel).
// INF arithmetic: 1e12f + r^2 rounds back to 1e12f for r^2 < 32768 in fp32
// (per-pass r^2 <= 159^2 = 25281) -> bit-exact vs the reference.

#define INF_F 1.0e12f

constexpr int NX = 160, NY = 160, NZ = 160, NB = 4;
constexpr int VOL   = NX * NY * NZ;        // 4,096,000 per batch
constexpr int TOTAL = NB * VOL;            // 16,384,000
constexpr int NROWS = NB * NZ * NY;        // 102,400 x-rows
constexpr int BLK   = 256;

__device__ inline float4 f4max(float4 a, float4 b) {
    return make_float4(fmaxf(a.x, b.x), fmaxf(a.y, b.y),
                       fmaxf(a.z, b.z), fmaxf(a.w, b.w));
}

// ---------------------------------------------------------------------------
// Wave-wide inclusive prefix-max / suffix-min scans (64 lanes).
__device__ inline int wave_prefmax(int v) {
    #pragma unroll
    for (int off = 1; off < 64; off <<= 1) {
        int o = __shfl_up(v, off, 64);
        v = max(v, o);
    }
    return v;
}
__device__ inline int wave_sufmin(int v) {
    #pragma unroll
    for (int off = 1; off < 64; off <<= 1) {
        int o = __shfl_down(v, off, 64);
        v = min(v, o);
    }
    return v;
}

__device__ inline float edt1d_combine(int x, int lz, int rz) {
    float dl2 = (lz >= 0)   ? (float)((x - lz) * (x - lz)) : INF_F;
    float dr2 = (rz < 1000) ? (float)((rz - x) * (rz - x)) : INF_F;
    return fminf(dl2, dr2);
}

// ---------------------------------------------------------------------------
// Pass 1 (along X): exact binary 1-D EDT via wave scans. One wave per row.
__global__ void edt_pass_x_scan(const float* __restrict__ img,
                                float* __restrict__ out) {
    int gw = blockIdx.x * (BLK / 64) + (threadIdx.x >> 6);
    if (gw >= NROWS) return;
    int lane = threadIdx.x & 63;
    int b = gw * NX;

    float a0 = img[b + lane];
    float a1 = img[b + 64 + lane];
    float a2 = (lane < 32) ? img[b + 128 + lane] : 0.0f;
    bool z0 = a0 > 0.5f;
    bool z1 = a1 > 0.5f;
    bool z2 = (lane < 32) && (a2 > 0.5f);

    const int NEG = -1048576, POS = 1048576;

    int l0 = wave_prefmax(z0 ? lane : NEG);
    int c  = __shfl(l0, 63, 64);
    int l1 = max(wave_prefmax(z1 ? 64 + lane : NEG), c);
    c      = __shfl(l1, 63, 64);
    int l2 = max(wave_prefmax(z2 ? 128 + lane : NEG), c);

    int r2v = wave_sufmin(z2 ? 128 + lane : POS);
    int cr  = __shfl(r2v, 0, 64);
    int r1  = min(wave_sufmin(z1 ? 64 + lane : POS), cr);
    cr      = __shfl(r1, 0, 64);
    int r0  = min(wave_sufmin(z0 ? lane : POS), cr);

    out[b + lane]      = edt1d_combine(lane,       l0, r0);
    out[b + 64 + lane] = edt1d_combine(64 + lane,  l1, r1);
    if (lane < 32)
        out[b + 128 + lane] = edt1d_combine(128 + lane, l2, r2v);
}

// ---------------------------------------------------------------------------
// Passes 2/3 (axis stride S, length 160), 4 voxels per thread.
template <int S>
__global__ void edt_pass_axis4(const float* __restrict__ g,
                               float* __restrict__ out) {
    int tid = blockIdx.x * BLK + threadIdx.x;
    if (tid >= TOTAL / 4) return;
    int idx4 = tid * 4;
    int c = (idx4 / S) % 160;
    float4 cur = *reinterpret_cast<const float4*>(g + idx4);
    float r2 = 1.0f, odd = 1.0f;
    for (int r = 1; r < 160; ++r) {
        float m = fmaxf(fmaxf(cur.x, cur.y), fmaxf(cur.z, cur.w));
        if (r2 >= m) break;
        if (c - r >= 0) {
            float4 u = *reinterpret_cast<const float4*>(g + idx4 - r * S);
            cur.x = fminf(cur.x, u.x + r2); cur.y = fminf(cur.y, u.y + r2);
            cur.z = fminf(cur.z, u.z + r2); cur.w = fminf(cur.w, u.w + r2);
        }
        if (c + r < 160) {
            float4 d = *reinterpret_cast<const float4*>(g + idx4 + r * S);
            cur.x = fminf(cur.x, d.x + r2); cur.y = fminf(cur.y, d.y + r2);
            cur.z = fminf(cur.z, d.z + r2); cur.w = fminf(cur.w, d.w + r2);
        }
        odd += 2.0f; r2 += odd;
    }
    *reinterpret_cast<float4*>(out + idx4) = cur;
}

// ---------------------------------------------------------------------------
// Skeleton v3: 4x2x2 tile (16 outputs) per thread. All 48 window loads issued
// up-front into statically-indexed arrays -> deep MLP; replicate-clamp
// boundaries (decision-identical to skip-OOB for a max window).
constexpr int NX4 = NX / 4, NY2 = NY / 2, NZ2 = NZ / 2;
constexpr int NTILE = NB * NZ2 * NY2 * NX4;   // 1,024,000 threads

__global__ void skel_kernel3(const float* __restrict__ d2,
                             const float* __restrict__ img,
                             float* __restrict__ out) {
    int tid = blockIdx.x * BLK + threadIdx.x;
    if (tid >= NTILE) return;
    int x4 = (tid % NX4) * 4;
    int t  = tid / NX4;
    int y  = (t % NY2) * 2;
    t /= NY2;
    int z  = (t % NZ2) * 2;
    int b  = t / NZ2;

    int base = ((b * NZ + z) * NY + y) * NX;   // row (b,z,y), x=0
    // rows y-1,y,y+1,y+2 and z-1,z,z+1,z+2, replicate-clamped
    const int yo[4] = { (y > 0) ? -NX : 0, 0, NX,
                        (y + 2 < NY) ? 2 * NX : NX };
    const int zo[4] = { (z > 0) ? -NX * NY : 0, 0, NX * NY,
                        (z + 2 < NZ) ? 2 * NX * NY : NX * NY };
    const int xl = (x4 > 0) ? x4 - 1 : 0;
    const int xr = (x4 + 4 < NX) ? x4 + 4 : NX - 1;

    // ---- phase 1: issue all 48 loads (static indexing; full unroll) ----
    float4 m[4][4];
    float  L[4][4], R[4][4];
    #pragma unroll
    for (int iz = 0; iz < 4; ++iz) {
        #pragma unroll
        for (int iy = 0; iy < 4; ++iy) {
            const float* row = d2 + base + zo[iz] + yo[iy];
            m[iz][iy] = *reinterpret_cast<const float4*>(row + x4);
            L[iz][iy] = row[xl];
            R[iz][iy] = row[xr];
        }
    }

    // ---- phase 2: horizontal 3-window max per row ----
    float4 h[4][4];
    #pragma unroll
    for (int iz = 0; iz < 4; ++iz) {
        #pragma unroll
        for (int iy = 0; iy < 4; ++iy) {
            float4 v = m[iz][iy];
            h[iz][iy] = make_float4(
                fmaxf(fmaxf(L[iz][iy], v.x), v.y),
                fmaxf(fmaxf(v.x, v.y), v.z),
                fmaxf(fmaxf(v.y, v.z), v.w),
                fmaxf(fmaxf(v.z, v.w), R[iz][iy]));
        }
    }

    // ---- phase 3: fold y then z; emit 4 outputs ----
    float4 cm[4][2];
    #pragma unroll
    for (int iz = 0; iz < 4; ++iz) {
        cm[iz][0] = f4max(f4max(h[iz][0], h[iz][1]), h[iz][2]);
        cm[iz][1] = f4max(f4max(h[iz][1], h[iz][2]), h[iz][3]);
    }

    #pragma unroll
    for (int oz = 0; oz < 2; ++oz) {
        #pragma unroll
        for (int oy = 0; oy < 2; ++oy) {
            float4 mx = f4max(f4max(cm[oz][oy], cm[oz + 1][oy]), cm[oz + 2][oy]);
            float4 ctr = m[oz + 1][oy + 1];
            int o = base + oz * NX * NY + oy * NX + x4;
            float4 iv = *reinterpret_cast<const float4*>(img + o);
            float4 ov;
            ov.x = (ctr.x >= mx.x && ctr.x > 0.0f) ? iv.x : 0.0f;
            ov.y = (ctr.y >= mx.y && ctr.y > 0.0f) ? iv.y : 0.0f;
            ov.z = (ctr.z >= mx.z && ctr.z > 0.0f) ? iv.z : 0.0f;
            ov.w = (ctr.w >= mx.w && ctr.w > 0.0f) ? iv.w : 0.0f;
            *reinterpret_cast<float4*>(out + o) = ov;
        }
    }
}

// ---------------------------------------------------------------------------
extern "C" void kernel_launch(void* const* d_in, const int* in_sizes, int n_in,
                              void* d_out, int out_size, void* d_ws, size_t ws_size,
                              hipStream_t stream) {
    const float* img = (const float*)d_in[0];
    float* outp = (float*)d_out;
    float* ws   = (float*)d_ws;             // needs >= TOTAL*4 = 65.5 MB

    int gridRows = (NROWS + 3) / 4;               // X-scan: 4 rows/block
    int grid4    = (TOTAL / 4 + BLK - 1) / BLK;   // 16,000 blocks
    int gridT    = (NTILE + BLK - 1) / BLK;       // 4,000 blocks

    // K1: X-pass (wave-scan binary EDT): img -> ws
    edt_pass_x_scan<<<gridRows, BLK, 0, stream>>>(img, ws);
    // K2: Y-pass (stride 160), 4-wide: ws -> d_out (scratch)
    edt_pass_axis4<NX><<<grid4, BLK, 0, stream>>>(ws, outp);
    // K3: Z-pass (stride 25600), 4-wide: d_out -> ws
    edt_pass_axis4<NX * NY><<<grid4, BLK, 0, stream>>>(outp, ws);
    // K4: skeleton + multiply, 4x2x2 tile/thread: (ws = final d2, img) -> d_out
    skel_kernel3<<<gridT, BLK, 0, stream>>>(ws, img, outp);
}